// Round 1
// baseline (316.792 us; speedup 1.0000x reference)
//
#include <hip/hip_runtime.h>
#include <hip/hip_fp16.h>

// Problem constants (from reference)
#define BB 8
#define NN 10000
#define TT 2000
#define SS 12
#define HH 128
#define TOTAL_E (BB * NN)           // 80000
#define COEF 1.2615662610100802f    // GAUSS_NORM / sqrt(BIN_SIGMA)

// Truncation radius: exp(-5*d*d) < 3e-20 for |d|>3; contributions beyond are
// ~1e-12 absolute vs threshold 165. Window is at most 7 ticks.
#define RADIUS 3.0f

__global__ __launch_bounds__(256) void sensor_kernel(
    const float* __restrict__ de,    // (B,N,3)
    const float* __restrict__ mask,  // (B,N)
    const float* __restrict__ W1,    // (3,128)
    const float* __restrict__ b1,    // (128)
    const float* __restrict__ W2,    // (128,128)
    const float* __restrict__ b2,    // (128)
    const float* __restrict__ W3,    // (128,12)
    const float* __restrict__ b3,    // (12)
    float* __restrict__ out)         // (B,12,2000)
{
    // LDS: W2 as fp16 (32 KB) + per-pass buffers. Total ~41 KB -> 3 blocks/CU.
    __shared__ __half sW2h[HH * HH];
    __shared__ float sh1[2][4][HH];
    __shared__ float sh2[2][4][HH];
    __shared__ float sresp[2][4][SS];
    __shared__ float sz[2][4];
    __shared__ float scoef[2][4];

    const int tid = threadIdx.x;
    const int g = tid >> 7;      // group 0/1 (128 threads each)
    const int j = tid & 127;     // position within group = H index

    // Stage W2 -> LDS (fp16). Row-major [k][j]: lane j reads W2[k*128+j],
    // consecutive lanes -> consecutive half-words -> conflict-free.
    for (int i = tid; i < HH * HH; i += 256)
        sW2h[i] = __float2half(W2[i]);
    __syncthreads();

    const float b1j = b1[j];
    const float b2j = b2[j];
    const float w1_0 = W1[j];
    const float w1_1 = W1[HH + j];
    const float w1_2 = W1[2 * HH + j];

    // Each block pass: 8 electrons (4 per group).
    for (int base = blockIdx.x * 8; base < TOTAL_E; base += gridDim.x * 8) {
        const int m0 = base + g * 4;

        // ---- stage 1: h1 = relu(x @ W1 + b1) for 4 electrons ----
        #pragma unroll
        for (int e = 0; e < 4; ++e) {
            const int m = m0 + e;
            const float x0 = de[m * 3 + 0];
            const float x1 = de[m * 3 + 1];
            const float x2 = de[m * 3 + 2];
            float h = fmaf(x2, w1_2, fmaf(x1, w1_1, fmaf(x0, w1_0, b1j)));
            sh1[g][e][j] = h > 0.f ? h : 0.f;
            if (j == e) {
                sz[g][e] = x2;
                scoef[g][e] = mask[m] * COEF;
            }
        }
        __syncthreads();

        // ---- stage 2: h2 = relu(h1 @ W2 + b2), 4 electrons share W2 reads ----
        float acc0 = b2j, acc1 = b2j, acc2 = b2j, acc3 = b2j;
        {
            const float4* h1a = (const float4*)sh1[g][0];
            const float4* h1b = (const float4*)sh1[g][1];
            const float4* h1c = (const float4*)sh1[g][2];
            const float4* h1d = (const float4*)sh1[g][3];
            #pragma unroll 8
            for (int k4 = 0; k4 < HH / 4; ++k4) {
                const float w0 = __half2float(sW2h[(k4 * 4 + 0) * HH + j]);
                const float w1 = __half2float(sW2h[(k4 * 4 + 1) * HH + j]);
                const float w2 = __half2float(sW2h[(k4 * 4 + 2) * HH + j]);
                const float w3 = __half2float(sW2h[(k4 * 4 + 3) * HH + j]);
                const float4 a = h1a[k4];
                const float4 b = h1b[k4];
                const float4 c = h1c[k4];
                const float4 d = h1d[k4];
                acc0 = fmaf(a.w, w3, fmaf(a.z, w2, fmaf(a.y, w1, fmaf(a.x, w0, acc0))));
                acc1 = fmaf(b.w, w3, fmaf(b.z, w2, fmaf(b.y, w1, fmaf(b.x, w0, acc1))));
                acc2 = fmaf(c.w, w3, fmaf(c.z, w2, fmaf(c.y, w1, fmaf(c.x, w0, acc2))));
                acc3 = fmaf(d.w, w3, fmaf(d.z, w2, fmaf(d.y, w1, fmaf(d.x, w0, acc3))));
            }
        }
        sh2[g][0][j] = acc0 > 0.f ? acc0 : 0.f;
        sh2[g][1][j] = acc1 > 0.f ? acc1 : 0.f;
        sh2[g][2][j] = acc2 > 0.f ? acc2 : 0.f;
        sh2[g][3][j] = acc3 > 0.f ? acc3 : 0.f;
        __syncthreads();

        // ---- stage 3: response = h2 @ W3 + b3 (48 threads: 4 electrons x 12) ----
        if (j < 4 * SS) {
            const int e = j / SS;
            const int s = j - e * SS;
            float r = b3[s];
            const float* h2e = sh2[g][e];
            #pragma unroll 8
            for (int k = 0; k < HH; ++k)
                r = fmaf(h2e[k], W3[k * SS + s], r);
            sresp[g][e][s] = r;
        }
        __syncthreads();

        // ---- stage 4: Gaussian scatter into out[b][s][t] ----
        #pragma unroll
        for (int e = 0; e < 4; ++e) {
            const float z = sz[g][e];
            const float cf = scoef[g][e];
            int t0 = (int)ceilf(z - RADIUS);
            if (t0 < 0) t0 = 0;
            int t1 = (int)floorf(z + RADIUS);
            if (t1 > TT - 1) t1 = TT - 1;
            const int cnt = t1 - t0 + 1;          // <= 7
            const int ti = j / SS;                // pair = (tick, s)
            const int s = j - ti * SS;
            if (ti < cnt) {
                const int t = t0 + ti;
                const float d = (float)t - z;
                const float w = __expf(-5.0f * d * d) * cf;
                const int m = m0 + e;
                const int bi = m / NN;
                atomicAdd(&out[(bi * SS + s) * TT + t], w * sresp[g][e][s]);
            }
        }
        __syncthreads();  // protect sh1/sz/sresp before next pass overwrites
    }
}

extern "C" void kernel_launch(void* const* d_in, const int* in_sizes, int n_in,
                              void* d_out, int out_size, void* d_ws, size_t ws_size,
                              hipStream_t stream) {
    const float* de   = (const float*)d_in[0];
    const float* mask = (const float*)d_in[1];
    const float* W1   = (const float*)d_in[2];
    const float* b1   = (const float*)d_in[3];
    const float* W2   = (const float*)d_in[4];
    const float* b2   = (const float*)d_in[5];
    const float* W3   = (const float*)d_in[6];
    const float* b3   = (const float*)d_in[7];
    float* out = (float*)d_out;

    // d_out is poisoned to 0xAA before every timed launch; zero it first.
    hipMemsetAsync(out, 0, (size_t)out_size * sizeof(float), stream);

    sensor_kernel<<<512, 256, 0, stream>>>(de, mask, W1, b1, W2, b2, W3, b3, out);
}

// Round 2
// 276.065 us; speedup vs baseline: 1.1475x; 1.1475x over previous
//
#include <hip/hip_runtime.h>
#include <hip/hip_fp16.h>

// Problem constants (from reference)
#define BB 8
#define NN 10000
#define TT 2000
#define SS 12
#define HH 128
#define TOTAL_E (BB * NN)           // 80000
#define COEF 1.2615662610100802f    // GAUSS_NORM / sqrt(BIN_SIGMA)
#define RADIUS 3.0f                 // exp(-5*9) ~ 3e-20: truncation error ~1e-12 abs

// Workspace layout (bytes)
#define WS_HIST   0            // 8*2000 u32   = 64000
#define WS_OFF    65536        // 8*2001 u32   = 64032
#define WS_CURSOR 131072       // 8*2000 u32   = 64000
#define WS_REC    196608       // 80000 * 16 f32 = 5,120,000  (z, coef, resp[12], pad2)
#define REC_F     16           // floats per record

// ---------------- K1: histogram of electrons by tick bin ----------------
__global__ __launch_bounds__(256) void hist_kernel(
    const float* __restrict__ de, unsigned int* __restrict__ hist)
{
    int m = blockIdx.x * blockDim.x + threadIdx.x;
    if (m >= TOTAL_E) return;
    float z = de[m * 3 + 2];
    int bin = (int)z;
    bin = bin < 0 ? 0 : (bin > TT - 1 ? TT - 1 : bin);
    int b = m / NN;
    atomicAdd(&hist[b * TT + bin], 1u);
}

// ---------------- K2: per-batch exclusive prefix scan (one block/batch) ----
__global__ __launch_bounds__(256) void scan_kernel(
    const unsigned int* __restrict__ hist,
    unsigned int* __restrict__ off,      // (B, T+1)
    unsigned int* __restrict__ cursor)   // (B, T)
{
    const int b = blockIdx.x;
    const int tid = threadIdx.x;
    __shared__ unsigned int partial[256];

    unsigned int vals[8];   // local exclusive prefix within this thread's chunk
    unsigned int s = 0;
    const int base = tid * 8;
    #pragma unroll
    for (int i = 0; i < 8; ++i) {
        int idx = base + i;
        unsigned int v = (idx < TT) ? hist[b * TT + idx] : 0u;
        vals[i] = s;
        s += v;
    }
    partial[tid] = s;
    __syncthreads();
    // Hillis-Steele inclusive scan over 256 partials
    for (int d = 1; d < 256; d <<= 1) {
        unsigned int t = (tid >= d) ? partial[tid - d] : 0u;
        __syncthreads();
        if (tid >= d) partial[tid] += t;
        __syncthreads();
    }
    unsigned int prev = (tid > 0) ? partial[tid - 1] : 0u;
    #pragma unroll
    for (int i = 0; i < 8; ++i) {
        int idx = base + i;
        if (idx < TT) {
            unsigned int o = prev + vals[i];
            off[b * (TT + 1) + idx] = o;
            cursor[b * TT + idx] = o;
        }
    }
    if (tid == 255) off[b * (TT + 1) + TT] = partial[255];  // == NN
}

// ---------------- K3: MLP + write sorted records ----------------
__global__ __launch_bounds__(256) void mlp_kernel(
    const float* __restrict__ de,    // (B,N,3)
    const float* __restrict__ mask,  // (B,N)
    const float* __restrict__ W1, const float* __restrict__ b1,
    const float* __restrict__ W2, const float* __restrict__ b2,
    const float* __restrict__ W3, const float* __restrict__ b3,
    unsigned int* __restrict__ cursor,
    float* __restrict__ rec)         // (TOTAL_E, 16)
{
    __shared__ __half sW2h[HH * HH];            // 32 KB
    __shared__ float sh1[2][4][HH];
    __shared__ float sh2[2][4][HH];
    __shared__ float sresp[2][4][SS];
    __shared__ float sz[2][4];
    __shared__ float scoef[2][4];
    __shared__ unsigned int spos[2][4];

    const int tid = threadIdx.x;
    const int g = tid >> 7;
    const int j = tid & 127;

    for (int i = tid; i < HH * HH; i += 256)
        sW2h[i] = __float2half(W2[i]);
    __syncthreads();

    const float b1j = b1[j];
    const float b2j = b2[j];
    const float w1_0 = W1[j];
    const float w1_1 = W1[HH + j];
    const float w1_2 = W1[2 * HH + j];

    for (int base = blockIdx.x * 8; base < TOTAL_E; base += gridDim.x * 8) {
        const int m0 = base + g * 4;

        // stage 1: h1 = relu(x @ W1 + b1)
        #pragma unroll
        for (int e = 0; e < 4; ++e) {
            const int m = m0 + e;
            const float x0 = de[m * 3 + 0];
            const float x1 = de[m * 3 + 1];
            const float x2 = de[m * 3 + 2];
            float h = fmaf(x2, w1_2, fmaf(x1, w1_1, fmaf(x0, w1_0, b1j)));
            sh1[g][e][j] = h > 0.f ? h : 0.f;
            if (j == e) {
                sz[g][e] = x2;
                scoef[g][e] = mask[m] * COEF;
            }
        }
        __syncthreads();

        // stage 2: h2 = relu(h1 @ W2 + b2) — 4 electrons share W2 LDS reads
        float acc0 = b2j, acc1 = b2j, acc2 = b2j, acc3 = b2j;
        {
            const float4* h1a = (const float4*)sh1[g][0];
            const float4* h1b = (const float4*)sh1[g][1];
            const float4* h1c = (const float4*)sh1[g][2];
            const float4* h1d = (const float4*)sh1[g][3];
            #pragma unroll 8
            for (int k4 = 0; k4 < HH / 4; ++k4) {
                const float w0 = __half2float(sW2h[(k4 * 4 + 0) * HH + j]);
                const float w1 = __half2float(sW2h[(k4 * 4 + 1) * HH + j]);
                const float w2 = __half2float(sW2h[(k4 * 4 + 2) * HH + j]);
                const float w3 = __half2float(sW2h[(k4 * 4 + 3) * HH + j]);
                const float4 a = h1a[k4];
                const float4 b = h1b[k4];
                const float4 c = h1c[k4];
                const float4 d = h1d[k4];
                acc0 = fmaf(a.w, w3, fmaf(a.z, w2, fmaf(a.y, w1, fmaf(a.x, w0, acc0))));
                acc1 = fmaf(b.w, w3, fmaf(b.z, w2, fmaf(b.y, w1, fmaf(b.x, w0, acc1))));
                acc2 = fmaf(c.w, w3, fmaf(c.z, w2, fmaf(c.y, w1, fmaf(c.x, w0, acc2))));
                acc3 = fmaf(d.w, w3, fmaf(d.z, w2, fmaf(d.y, w1, fmaf(d.x, w0, acc3))));
            }
        }
        sh2[g][0][j] = acc0 > 0.f ? acc0 : 0.f;
        sh2[g][1][j] = acc1 > 0.f ? acc1 : 0.f;
        sh2[g][2][j] = acc2 > 0.f ? acc2 : 0.f;
        sh2[g][3][j] = acc3 > 0.f ? acc3 : 0.f;
        __syncthreads();

        // stage 3: response = h2 @ W3 + b3 (48 threads per group)
        if (j < 4 * SS) {
            const int e = j / SS;
            const int s = j - e * SS;
            float r = b3[s];
            const float* h2e = sh2[g][e];
            #pragma unroll 8
            for (int k = 0; k < HH; ++k)
                r = fmaf(h2e[k], W3[k * SS + s], r);
            sresp[g][e][s] = r;
        }
        // stage 3b: claim sorted slot (1 thread per electron)
        if (j < 4) {
            const int e = j;
            const int m = m0 + e;
            const int bi = m / NN;
            float z = sz[g][e];
            int bin = (int)z;
            bin = bin < 0 ? 0 : (bin > TT - 1 ? TT - 1 : bin);
            spos[g][e] = atomicAdd(&cursor[bi * TT + bin], 1u);
        }
        __syncthreads();

        // stage 4: write 64B record into sorted position (64 threads/group)
        if (j < 64) {
            const int e = j >> 4;
            const int f = j & 15;
            const int m = m0 + e;
            const int bi = m / NN;
            float v;
            if (f == 0)       v = sz[g][e];
            else if (f == 1)  v = scoef[g][e];
            else if (f < 14)  v = sresp[g][e][f - 2];
            else              v = 0.f;
            rec[((size_t)(bi * NN + spos[g][e])) * REC_F + f] = v;
        }
        __syncthreads();
    }
}

// ---------------- K4: gather — out[b][s][t] = sum over nearby electrons ----
__global__ __launch_bounds__(256) void gather_kernel(
    const unsigned int* __restrict__ off,  // (B, T+1)
    const float* __restrict__ rec,         // (TOTAL_E, 16)
    float* __restrict__ out)               // (B, S, T)
{
    const int gidx = blockIdx.x * blockDim.x + threadIdx.x;  // 192000 threads
    const int t = gidx % TT;
    const int s = (gidx / TT) % SS;
    const int b = gidx / (TT * SS);

    int lo = t - 4; if (lo < 0) lo = 0;
    int hi = t + 3; if (hi > TT - 1) hi = TT - 1;
    const unsigned int i0 = off[b * (TT + 1) + lo];
    const unsigned int i1 = off[b * (TT + 1) + hi + 1];

    const float tf = (float)t;
    float acc = 0.f;
    for (unsigned int i = i0; i < i1; ++i) {
        const float* r = rec + ((size_t)(b * NN + i)) * REC_F;
        const float z = r[0];
        const float c = r[1];
        const float d = tf - z;
        acc = fmaf(__expf(-5.0f * d * d) * c, r[2 + s], acc);
    }
    out[(b * SS + s) * TT + t] = acc;
}

extern "C" void kernel_launch(void* const* d_in, const int* in_sizes, int n_in,
                              void* d_out, int out_size, void* d_ws, size_t ws_size,
                              hipStream_t stream) {
    const float* de   = (const float*)d_in[0];
    const float* mask = (const float*)d_in[1];
    const float* W1   = (const float*)d_in[2];
    const float* b1   = (const float*)d_in[3];
    const float* W2   = (const float*)d_in[4];
    const float* b2   = (const float*)d_in[5];
    const float* W3   = (const float*)d_in[6];
    const float* b3   = (const float*)d_in[7];
    float* out = (float*)d_out;

    char* ws = (char*)d_ws;
    unsigned int* hist   = (unsigned int*)(ws + WS_HIST);
    unsigned int* off    = (unsigned int*)(ws + WS_OFF);
    unsigned int* cursor = (unsigned int*)(ws + WS_CURSOR);
    float*        rec    = (float*)(ws + WS_REC);

    // hist must be zeroed every call (ws re-poisoned to 0xAA).
    hipMemsetAsync(hist, 0, BB * TT * sizeof(unsigned int), stream);

    hist_kernel<<<(TOTAL_E + 255) / 256, 256, 0, stream>>>(de, hist);
    scan_kernel<<<BB, 256, 0, stream>>>(hist, off, cursor);
    mlp_kernel<<<768, 256, 0, stream>>>(de, mask, W1, b1, W2, b2, W3, b3, cursor, rec);
    gather_kernel<<<(BB * SS * TT) / 256, 256, 0, stream>>>(off, rec, out);
}

// Round 3
// 127.351 us; speedup vs baseline: 2.4875x; 2.1677x over previous
//
#include <hip/hip_runtime.h>
#include <hip/hip_fp16.h>

// Problem constants (from reference)
#define BB 8
#define NN 10000
#define TT 2000
#define SS 12
#define HH 128
#define TOTAL_E (BB * NN)           // 80000
#define COEF 1.2615662610100802f    // GAUSS_NORM / sqrt(BIN_SIGMA)

// Workspace layout (bytes)
#define WS_HIST   0            // 8*2000 u32
#define WS_OFF    65536        // 8*2001 u32
#define WS_CURSOR 131072       // 8*2000 u32
#define WS_REC    196608       // 80000 * 16 f32 (z, coef, resp[12], pad2)
#define REC_F     16

typedef _Float16 half8 __attribute__((ext_vector_type(8)));
typedef float f32x4 __attribute__((ext_vector_type(4)));

#define LDK 136   // LDS row stride in halves (272 B: 16B-aligned, 2-way banks max)

// ---------------- K1: histogram of electrons by tick bin ----------------
__global__ __launch_bounds__(256) void hist_kernel(
    const float* __restrict__ de, unsigned int* __restrict__ hist)
{
    int m = blockIdx.x * blockDim.x + threadIdx.x;
    if (m >= TOTAL_E) return;
    float z = de[m * 3 + 2];
    int bin = (int)z;
    bin = bin < 0 ? 0 : (bin > TT - 1 ? TT - 1 : bin);
    int b = m / NN;
    atomicAdd(&hist[b * TT + bin], 1u);
}

// ---------------- K2: per-batch exclusive prefix scan ----------------
__global__ __launch_bounds__(256) void scan_kernel(
    const unsigned int* __restrict__ hist,
    unsigned int* __restrict__ off,      // (B, T+1)
    unsigned int* __restrict__ cursor)   // (B, T)
{
    const int b = blockIdx.x;
    const int tid = threadIdx.x;
    __shared__ unsigned int partial[256];

    unsigned int vals[8];
    unsigned int s = 0;
    const int base = tid * 8;
    #pragma unroll
    for (int i = 0; i < 8; ++i) {
        int idx = base + i;
        unsigned int v = (idx < TT) ? hist[b * TT + idx] : 0u;
        vals[i] = s;
        s += v;
    }
    partial[tid] = s;
    __syncthreads();
    for (int d = 1; d < 256; d <<= 1) {
        unsigned int t = (tid >= d) ? partial[tid - d] : 0u;
        __syncthreads();
        if (tid >= d) partial[tid] += t;
        __syncthreads();
    }
    unsigned int prev = (tid > 0) ? partial[tid - 1] : 0u;
    #pragma unroll
    for (int i = 0; i < 8; ++i) {
        int idx = base + i;
        if (idx < TT) {
            unsigned int o = prev + vals[i];
            off[b * (TT + 1) + idx] = o;
            cursor[b * TT + idx] = o;
        }
    }
    if (tid == 255) off[b * (TT + 1) + TT] = partial[255];
}

// ---------------- K3: fully-MFMA MLP + sorted record write ----------------
// Block = 256 thr = 4 waves; each wave owns 16 electrons; grid 1250 blocks.
// Layer chain: x(16x32,pad) @ W1 -> h1 -> LDS -> h1 @ W2(LDS-resident B-frags)
// -> h2 -> LDS -> h2 @ W3 -> resp. MFMA f16, f32 accum.
__global__ __launch_bounds__(256) void mlp_kernel(
    const float* __restrict__ de,    // (B,N,3)
    const float* __restrict__ mask,  // (B,N)
    const float* __restrict__ W1, const float* __restrict__ b1,
    const float* __restrict__ W2, const float* __restrict__ b2,
    const float* __restrict__ W3, const float* __restrict__ b3,
    unsigned int* __restrict__ cursor,
    float* __restrict__ rec)         // (TOTAL_E, 16)
{
    __shared__ _Float16 sW2T[HH * LDK];   // [n][k] transposed, 34.8 KB
    __shared__ _Float16 sh[64 * LDK];     // [m][k] h1 then h2, 17.4 KB

    const int tid = threadIdx.x;
    const int wave = tid >> 6;
    const int lane = tid & 63;
    const int q = lane >> 4;      // quad 0..3
    const int i = lane & 15;      // n-index / m-index within tile

    // ---- stage W2 -> LDS transposed f16 ----
    {
        const int k = tid >> 1;               // 0..127
        const int n0 = (tid & 1) * 64;
        const float4* src = (const float4*)(W2 + k * HH + n0);
        #pragma unroll
        for (int c = 0; c < 16; ++c) {
            float4 v = src[c];
            int n = n0 + c * 4;
            sW2T[(n + 0) * LDK + k] = (_Float16)v.x;
            sW2T[(n + 1) * LDK + k] = (_Float16)v.y;
            sW2T[(n + 2) * LDK + k] = (_Float16)v.z;
            sW2T[(n + 3) * LDK + k] = (_Float16)v.w;
        }
    }

    // ---- per-lane electron data ----
    const int m_glob = blockIdx.x * 64 + wave * 16 + i;
    const int bi = m_glob / NN;
    const float x0 = de[m_glob * 3 + 0];
    const float x1 = de[m_glob * 3 + 1];
    const float x2 = de[m_glob * 3 + 2];   // = z
    const float coef = mask[m_glob] * COEF;

    // ---- preload small fragments / biases ----
    half8 aX = {};
    if (q == 0) { aX[0] = (_Float16)x0; aX[1] = (_Float16)x1; aX[2] = (_Float16)x2; }

    half8 bW1[8];
    #pragma unroll
    for (int nt = 0; nt < 8; ++nt) {
        half8 f = {};
        if (q == 0) {
            int n = nt * 16 + i;
            f[0] = (_Float16)W1[n];
            f[1] = (_Float16)W1[HH + n];
            f[2] = (_Float16)W1[2 * HH + n];
        }
        bW1[nt] = f;
    }
    half8 bW3[4];
    #pragma unroll
    for (int c = 0; c < 4; ++c) {
        half8 f = {};
        if (i < SS) {
            #pragma unroll
            for (int j = 0; j < 8; ++j)
                f[j] = (_Float16)W3[(c * 32 + q * 8 + j) * SS + i];
        }
        bW3[c] = f;
    }
    float b1v[8], b2v[8];
    #pragma unroll
    for (int nt = 0; nt < 8; ++nt) {
        b1v[nt] = b1[nt * 16 + i];
        b2v[nt] = b2[nt * 16 + i];
    }
    const float b3v = (i < SS) ? b3[i] : 0.f;

    __syncthreads();  // W2T staged

    // ---- S1: h1 = relu(x @ W1 + b1) via MFMA (K=32, only k<3 nonzero) ----
    const int mrow = wave * 16;
    {
        #pragma unroll
        for (int nt = 0; nt < 8; ++nt) {
            f32x4 acc = {};
            acc = __builtin_amdgcn_mfma_f32_16x16x32_f16(aX, bW1[nt], acc, 0, 0, 0);
            #pragma unroll
            for (int r = 0; r < 4; ++r) {
                float v = acc[r] + b1v[nt];
                v = v > 0.f ? v : 0.f;
                sh[(mrow + q * 4 + r) * LDK + nt * 16 + i] = (_Float16)v;
            }
        }
    }
    __syncthreads();  // h1 visible

    // ---- S2: h2 = relu(h1 @ W2 + b2) ----
    half8 aH[4];
    #pragma unroll
    for (int c = 0; c < 4; ++c)
        aH[c] = *(const half8*)(sh + (mrow + i) * LDK + c * 32 + q * 8);
    __syncthreads();  // all A-reads done before overwrite

    f32x4 acc2[8];
    #pragma unroll
    for (int nt = 0; nt < 8; ++nt) acc2[nt] = (f32x4){};
    #pragma unroll
    for (int nt = 0; nt < 8; ++nt) {
        #pragma unroll
        for (int c = 0; c < 4; ++c) {
            half8 bf = *(const half8*)(sW2T + (nt * 16 + i) * LDK + c * 32 + q * 8);
            acc2[nt] = __builtin_amdgcn_mfma_f32_16x16x32_f16(aH[c], bf, acc2[nt], 0, 0, 0);
        }
    }
    #pragma unroll
    for (int nt = 0; nt < 8; ++nt) {
        #pragma unroll
        for (int r = 0; r < 4; ++r) {
            float v = acc2[nt][r] + b2v[nt];
            v = v > 0.f ? v : 0.f;
            sh[(mrow + q * 4 + r) * LDK + nt * 16 + i] = (_Float16)v;
        }
    }
    __syncthreads();  // h2 visible

    // ---- S3: resp = h2 @ W3 + b3 ----
    f32x4 acc3 = {};
    #pragma unroll
    for (int c = 0; c < 4; ++c) {
        half8 a2 = *(const half8*)(sh + (mrow + i) * LDK + c * 32 + q * 8);
        acc3 = __builtin_amdgcn_mfma_f32_16x16x32_f16(a2, bW3[c], acc3, 0, 0, 0);
    }

    // ---- claim sorted slot (lanes 0..15 = electrons) ----
    unsigned int pos = 0;
    if (lane < 16) {
        int bin = (int)x2;
        bin = bin < 0 ? 0 : (bin > TT - 1 ? TT - 1 : bin);
        pos = atomicAdd(&cursor[bi * TT + bin], 1u);
    }

    // ---- write records: lane (q, s=i) writes field for electrons q*4+r ----
    #pragma unroll
    for (int r = 0; r < 4; ++r) {
        const int e = q * 4 + r;                       // electron within wave
        const unsigned int posr = __shfl(pos, e);
        const float zr   = __shfl(x2, e);
        const float cr   = __shfl(coef, e);
        const int   bir  = __shfl(bi, e);
        float val;
        int f;
        if (i < SS)       { val = acc3[r] + b3v; f = 2 + i; }
        else if (i == 12) { val = zr;            f = 0; }
        else              { val = cr;            f = 1; }
        if (i < 14)
            rec[((size_t)(bir * NN + posr)) * REC_F + f] = val;
    }
}

// ---------------- K4: gather — thread = (b, s, tick-pair) ----------------
__global__ __launch_bounds__(256) void gather_kernel(
    const unsigned int* __restrict__ off,  // (B, T+1)
    const float* __restrict__ rec,         // (TOTAL_E, 16)
    float* __restrict__ out)               // (B, S, T)
{
    const int gid = blockIdx.x * blockDim.x + threadIdx.x;  // 96000
    if (gid >= BB * SS * (TT / 2)) return;
    const int th = gid % (TT / 2);
    const int s = (gid / (TT / 2)) % SS;
    const int b = gid / ((TT / 2) * SS);
    const int t0 = th * 2;

    int lo = t0 - 3; if (lo < 0) lo = 0;
    int hi = t0 + 3; if (hi > TT - 1) hi = TT - 1;
    const unsigned int i0 = off[b * (TT + 1) + lo];
    const unsigned int i1 = off[b * (TT + 1) + hi + 1];

    const float tf0 = (float)t0;
    const float tf1 = (float)(t0 + 1);
    float a0 = 0.f, a1 = 0.f;
    for (unsigned int u = i0; u < i1; ++u) {
        const float* r = rec + ((size_t)(b * NN + u)) * REC_F;
        const float2 zc = *(const float2*)r;
        const float rs = r[2 + s];
        const float d0 = tf0 - zc.x;
        const float d1 = tf1 - zc.x;
        const float w0 = __expf(-5.0f * d0 * d0) * zc.y;
        const float w1 = __expf(-5.0f * d1 * d1) * zc.y;
        a0 = fmaf(w0, rs, a0);
        a1 = fmaf(w1, rs, a1);
    }
    float2 res; res.x = a0; res.y = a1;
    *(float2*)&out[(b * SS + s) * TT + t0] = res;
}

extern "C" void kernel_launch(void* const* d_in, const int* in_sizes, int n_in,
                              void* d_out, int out_size, void* d_ws, size_t ws_size,
                              hipStream_t stream) {
    const float* de   = (const float*)d_in[0];
    const float* mask = (const float*)d_in[1];
    const float* W1   = (const float*)d_in[2];
    const float* b1   = (const float*)d_in[3];
    const float* W2   = (const float*)d_in[4];
    const float* b2   = (const float*)d_in[5];
    const float* W3   = (const float*)d_in[6];
    const float* b3   = (const float*)d_in[7];
    float* out = (float*)d_out;

    char* ws = (char*)d_ws;
    unsigned int* hist   = (unsigned int*)(ws + WS_HIST);
    unsigned int* off    = (unsigned int*)(ws + WS_OFF);
    unsigned int* cursor = (unsigned int*)(ws + WS_CURSOR);
    float*        rec    = (float*)(ws + WS_REC);

    hipMemsetAsync(hist, 0, BB * TT * sizeof(unsigned int), stream);

    hist_kernel<<<(TOTAL_E + 255) / 256, 256, 0, stream>>>(de, hist);
    scan_kernel<<<BB, 256, 0, stream>>>(hist, off, cursor);
    mlp_kernel<<<TOTAL_E / 64, 256, 0, stream>>>(de, mask, W1, b1, W2, b2, W3, b3,
                                                 cursor, rec);
    gather_kernel<<<(BB * SS * (TT / 2) + 255) / 256, 256, 0, stream>>>(off, rec, out);
}

// Round 4
// 126.686 us; speedup vs baseline: 2.5006x; 1.0052x over previous
//
#include <hip/hip_runtime.h>
#include <hip/hip_fp16.h>

// Problem constants (from reference)
#define BB 8
#define NN 10000
#define TT 2000
#define SS 12
#define HH 128
#define TOTAL_E (BB * NN)           // 80000
#define COEF 1.2615662610100802f    // GAUSS_NORM / sqrt(BIN_SIGMA)

// Bucket sort: lambda = 10000/1999 ~ 5 electrons/bin; P(bin > 32) ~ 1e-16.
#define CAP 32
#define REC_F 16                    // floats per record (64 B): z, coef, resp[12], pad2

// Workspace layout (bytes)
#define WS_CURSOR 0                 // 8*2000 u32 = 64 KB (doubles as per-bin count)
#define WS_REC    65536             // 8*2000*32 records * 64 B = 32.8 MB

typedef _Float16 half8 __attribute__((ext_vector_type(8)));
typedef float f32x4 __attribute__((ext_vector_type(4)));

// Swizzled LDS addressing for [row][128 halves] tiles: 16 chunks of 8 halves
// (16 B) per row; phys_chunk = chunk ^ (row & 7). Rows are 256 B (bank-stride
// 0), the xor rotates the 4-bank groups so b128 frag reads are 2-way (free).
__device__ __forceinline__ int swz(int row, int chunk) {
    return row * 128 + ((chunk ^ (row & 7)) * 8);
}

// ---------------- K1: fully-MFMA MLP + bucketed record write ----------------
// Block = 256 thr = 4 waves; each wave owns 16 electrons/pass; 625 blocks x 2
// passes. x @ W1 -> h1 -> LDS -> h1 @ W2(LDS B-frags) -> h2 -> LDS -> h2 @ W3.
__global__ __launch_bounds__(256) void mlp_kernel(
    const float* __restrict__ de,    // (B,N,3)
    const float* __restrict__ mask,  // (B,N)
    const float* __restrict__ W1, const float* __restrict__ b1,
    const float* __restrict__ W2, const float* __restrict__ b2,
    const float* __restrict__ W3, const float* __restrict__ b3,
    unsigned int* __restrict__ cursor,
    float* __restrict__ rec)
{
    __shared__ _Float16 sW2T[HH * 128];   // [n][k] transposed, swizzled, 32 KB
    __shared__ _Float16 sh[64 * 128];     // [m][k] h1 then h2, swizzled, 16 KB

    const int tid = threadIdx.x;
    const int wave = tid >> 6;
    const int lane = tid & 63;
    const int q = lane >> 4;      // quad 0..3
    const int i = lane & 15;      // tile row/col index

    // ---- stage W2^T -> LDS (f16, swizzled, b128 writes) ----
    {
        const int n = tid >> 1;              // output-feature row 0..127
        const int kh = (tid & 1) * 8;        // k-chunk half 0..7 / 8..15
        #pragma unroll
        for (int c8 = 0; c8 < 8; ++c8) {
            const int c = kh + c8;
            half8 v;
            #pragma unroll
            for (int j = 0; j < 8; ++j)
                v[j] = (_Float16)W2[(c * 8 + j) * HH + n];   // W2[k][n]
            *(half8*)(sW2T + swz(n, c)) = v;
        }
    }

    // ---- loop-invariant fragments / biases ----
    half8 bW1[8];
    #pragma unroll
    for (int nt = 0; nt < 8; ++nt) {
        half8 f = {};
        if (q == 0) {
            const int n = nt * 16 + i;
            f[0] = (_Float16)W1[n];
            f[1] = (_Float16)W1[HH + n];
            f[2] = (_Float16)W1[2 * HH + n];
        }
        bW1[nt] = f;
    }
    half8 bW3[4];
    #pragma unroll
    for (int c = 0; c < 4; ++c) {
        half8 f = {};
        if (i < SS) {
            #pragma unroll
            for (int j = 0; j < 8; ++j)
                f[j] = (_Float16)W3[(c * 32 + q * 8 + j) * SS + i];
        }
        bW3[c] = f;
    }
    float b1v[8], b2v[8];
    #pragma unroll
    for (int nt = 0; nt < 8; ++nt) {
        b1v[nt] = b1[nt * 16 + i];
        b2v[nt] = b2[nt * 16 + i];
    }
    const float b3v = (i < SS) ? b3[i] : 0.f;

    __syncthreads();  // sW2T staged

    const int mrow = wave * 16;

    for (int base = blockIdx.x * 64; base < TOTAL_E; base += gridDim.x * 64) {
        const int m_glob = base + mrow + i;
        const int bi = m_glob / NN;
        const float x0 = de[m_glob * 3 + 0];
        const float x1 = de[m_glob * 3 + 1];
        const float x2 = de[m_glob * 3 + 2];   // = z
        const float coef = mask[m_glob] * COEF;

        half8 aX = {};
        if (q == 0) { aX[0] = (_Float16)x0; aX[1] = (_Float16)x1; aX[2] = (_Float16)x2; }

        // ---- S1: h1 = relu(x @ W1 + b1) ----
        #pragma unroll
        for (int nt = 0; nt < 8; ++nt) {
            f32x4 acc = {};
            acc = __builtin_amdgcn_mfma_f32_16x16x32_f16(aX, bW1[nt], acc, 0, 0, 0);
            #pragma unroll
            for (int r = 0; r < 4; ++r) {
                float v = acc[r] + b1v[nt];
                v = v > 0.f ? v : 0.f;
                const int row = mrow + q * 4 + r;
                const int col = nt * 16 + i;
                sh[swz(row, col >> 3) + (col & 7)] = (_Float16)v;
            }
        }
        __syncthreads();  // h1 visible

        // ---- S2: h2 = relu(h1 @ W2 + b2) ----
        half8 aH[4];
        #pragma unroll
        for (int c = 0; c < 4; ++c)
            aH[c] = *(const half8*)(sh + swz(mrow + i, c * 4 + q));
        __syncthreads();  // all h1 reads done before h2 overwrite

        f32x4 acc2[8];
        #pragma unroll
        for (int nt = 0; nt < 8; ++nt) acc2[nt] = (f32x4){};
        #pragma unroll
        for (int nt = 0; nt < 8; ++nt) {
            #pragma unroll
            for (int c = 0; c < 4; ++c) {
                half8 bf = *(const half8*)(sW2T + swz(nt * 16 + i, c * 4 + q));
                acc2[nt] = __builtin_amdgcn_mfma_f32_16x16x32_f16(aH[c], bf, acc2[nt], 0, 0, 0);
            }
        }
        #pragma unroll
        for (int nt = 0; nt < 8; ++nt) {
            #pragma unroll
            for (int r = 0; r < 4; ++r) {
                float v = acc2[nt][r] + b2v[nt];
                v = v > 0.f ? v : 0.f;
                const int row = mrow + q * 4 + r;
                const int col = nt * 16 + i;
                sh[swz(row, col >> 3) + (col & 7)] = (_Float16)v;
            }
        }
        __syncthreads();  // h2 visible

        // ---- S3: resp = h2 @ W3 + b3 ----
        f32x4 acc3 = {};
        #pragma unroll
        for (int c = 0; c < 4; ++c) {
            half8 a2 = *(const half8*)(sh + swz(mrow + i, c * 4 + q));
            acc3 = __builtin_amdgcn_mfma_f32_16x16x32_f16(a2, bW3[c], acc3, 0, 0, 0);
        }

        // ---- claim bucket slot (lanes 0..15 = the wave's 16 electrons) ----
        unsigned int ridx = 0;
        if (lane < 16) {
            int bin = (int)x2;
            bin = bin < 0 ? 0 : (bin > TT - 1 ? TT - 1 : bin);
            unsigned int slot = atomicAdd(&cursor[bi * TT + bin], 1u);
            if (slot >= CAP) slot = CAP - 1;   // statistically unreachable
            ridx = (unsigned int)(bi * TT + bin) * CAP + slot;
        }

        // ---- write records: lane (q,i) covers electrons q*4+r, field i ----
        #pragma unroll
        for (int r = 0; r < 4; ++r) {
            const int e = q * 4 + r;
            const unsigned int rx = __shfl(ridx, e);
            const float zr = __shfl(x2, e);
            const float cr = __shfl(coef, e);
            float val;
            int f;
            if (i < SS)       { val = acc3[r] + b3v; f = 2 + i; }
            else if (i == 12) { val = zr;            f = 0; }
            else              { val = cr;            f = 1; }
            if (i < 14)
                rec[(size_t)rx * REC_F + f] = val;
        }
        __syncthreads();  // protect sh before next pass
    }
}

// ---------------- K2: gather — thread = (b, s, t) ----------------
__global__ __launch_bounds__(256) void gather_kernel(
    const unsigned int* __restrict__ cursor,  // per-bin counts
    const float* __restrict__ rec,
    float* __restrict__ out)                  // (B, S, T)
{
    const int gid = blockIdx.x * blockDim.x + threadIdx.x;  // 192000 exact
    const int t = gid % TT;
    const int s = (gid / TT) % SS;
    const int b = gid / (TT * SS);

    int lo = t - 3; if (lo < 0) lo = 0;
    int hi = t + 3; if (hi > TT - 1) hi = TT - 1;

    const float tf = (float)t;
    float acc = 0.f;
    for (int bin = lo; bin <= hi; ++bin) {
        unsigned int cnt = cursor[b * TT + bin];
        if (cnt > CAP) cnt = CAP;
        const float* rb = rec + (size_t)(b * TT + bin) * CAP * REC_F;
        for (unsigned int u = 0; u < cnt; ++u) {
            const float* r = rb + u * REC_F;
            const float2 zc = *(const float2*)r;
            const float d = tf - zc.x;
            acc = fmaf(__expf(-5.0f * d * d) * zc.y, r[2 + s], acc);
        }
    }
    out[(b * SS + s) * TT + t] = acc;
}

extern "C" void kernel_launch(void* const* d_in, const int* in_sizes, int n_in,
                              void* d_out, int out_size, void* d_ws, size_t ws_size,
                              hipStream_t stream) {
    const float* de   = (const float*)d_in[0];
    const float* mask = (const float*)d_in[1];
    const float* W1   = (const float*)d_in[2];
    const float* b1   = (const float*)d_in[3];
    const float* W2   = (const float*)d_in[4];
    const float* b2   = (const float*)d_in[5];
    const float* W3   = (const float*)d_in[6];
    const float* b3   = (const float*)d_in[7];
    float* out = (float*)d_out;

    char* ws = (char*)d_ws;
    unsigned int* cursor = (unsigned int*)(ws + WS_CURSOR);
    float*        rec    = (float*)(ws + WS_REC);

    // cursor doubles as histogram; must start at zero every call.
    hipMemsetAsync(cursor, 0, BB * TT * sizeof(unsigned int), stream);

    mlp_kernel<<<625, 256, 0, stream>>>(de, mask, W1, b1, W2, b2, W3, b3,
                                        cursor, rec);
    gather_kernel<<<(BB * SS * TT) / 256, 256, 0, stream>>>(cursor, rec, out);
}

// Round 5
// 106.942 us; speedup vs baseline: 2.9623x; 1.1846x over previous
//
#include <hip/hip_runtime.h>
#include <hip/hip_fp16.h>

// Problem constants (from reference)
#define BB 8
#define NN 10000
#define TT 2000
#define SS 12
#define HH 128
#define TOTAL_E (BB * NN)           // 80000
#define COEF 1.2615662610100802f    // GAUSS_NORM / sqrt(BIN_SIGMA)

// Bucket sort: lambda ~ 5 electrons/bin; P(bin > 32) ~ 1e-16.
#define CAP 32
#define REC_W 8                     // dwords per record (32 B): z, coef, resp[12] f16

// Gather tiling
#define TB 20                       // ticks per block
#define NB 26                       // bins staged = TB + 6

// Workspace layout (bytes)
#define WS_CURSOR 0                 // 8*2000 u32 = 64 KB
#define WS_REC    65536             // 8*2000*32 rec * 32 B = 16.4 MB

typedef _Float16 half8 __attribute__((ext_vector_type(8)));
typedef float f32x4 __attribute__((ext_vector_type(4)));

// Swizzled LDS addressing for [row][128 halves] tiles: 16 chunks of 8 halves;
// phys_chunk = chunk ^ (row & 7) -> b128 frag reads are 2-way (free).
__device__ __forceinline__ int swz(int row, int chunk) {
    return row * 128 + ((chunk ^ (row & 7)) * 8);
}

// ---------------- K1: fully-MFMA MLP + bucketed 32B record write ----------------
__global__ __launch_bounds__(256) void mlp_kernel(
    const float* __restrict__ de,    // (B,N,3)
    const float* __restrict__ mask,  // (B,N)
    const float* __restrict__ W1, const float* __restrict__ b1,
    const float* __restrict__ W2, const float* __restrict__ b2,
    const float* __restrict__ W3, const float* __restrict__ b3,
    unsigned int* __restrict__ cursor,
    float* __restrict__ rec)
{
    __shared__ _Float16 sW2T[HH * 128];   // [n][k] transposed, swizzled, 32 KB
    __shared__ _Float16 sh[64 * 128];     // [m][k] h1 then h2, swizzled, 16 KB

    const int tid = threadIdx.x;
    const int wave = tid >> 6;
    const int lane = tid & 63;
    const int q = lane >> 4;      // quad 0..3
    const int i = lane & 15;      // tile row/col index

    // ---- stage W2^T -> LDS (f16, swizzled, b128 writes) ----
    {
        const int n = tid >> 1;
        const int kh = (tid & 1) * 8;
        #pragma unroll
        for (int c8 = 0; c8 < 8; ++c8) {
            const int c = kh + c8;
            half8 v;
            #pragma unroll
            for (int j = 0; j < 8; ++j)
                v[j] = (_Float16)W2[(c * 8 + j) * HH + n];   // W2[k][n]
            *(half8*)(sW2T + swz(n, c)) = v;
        }
    }

    // ---- loop-invariant fragments / biases ----
    half8 bW1[8];
    #pragma unroll
    for (int nt = 0; nt < 8; ++nt) {
        half8 f = {};
        if (q == 0) {
            const int n = nt * 16 + i;
            f[0] = (_Float16)W1[n];
            f[1] = (_Float16)W1[HH + n];
            f[2] = (_Float16)W1[2 * HH + n];
        }
        bW1[nt] = f;
    }
    half8 bW3[4];
    #pragma unroll
    for (int c = 0; c < 4; ++c) {
        half8 f = {};
        if (i < SS) {
            #pragma unroll
            for (int j = 0; j < 8; ++j)
                f[j] = (_Float16)W3[(c * 32 + q * 8 + j) * SS + i];
        }
        bW3[c] = f;
    }
    float b1v[8], b2v[8];
    #pragma unroll
    for (int nt = 0; nt < 8; ++nt) {
        b1v[nt] = b1[nt * 16 + i];
        b2v[nt] = b2[nt * 16 + i];
    }
    const float b3v = (i < SS) ? b3[i] : 0.f;

    __syncthreads();  // sW2T staged

    const int mrow = wave * 16;

    for (int base = blockIdx.x * 64; base < TOTAL_E; base += gridDim.x * 64) {
        const int m_glob = base + mrow + i;
        const int bi = m_glob / NN;
        const float x0 = de[m_glob * 3 + 0];
        const float x1 = de[m_glob * 3 + 1];
        const float x2 = de[m_glob * 3 + 2];   // = z
        const float coef = mask[m_glob] * COEF;

        half8 aX = {};
        if (q == 0) { aX[0] = (_Float16)x0; aX[1] = (_Float16)x1; aX[2] = (_Float16)x2; }

        // ---- S1: h1 = relu(x @ W1 + b1) ----
        #pragma unroll
        for (int nt = 0; nt < 8; ++nt) {
            f32x4 acc = {};
            acc = __builtin_amdgcn_mfma_f32_16x16x32_f16(aX, bW1[nt], acc, 0, 0, 0);
            #pragma unroll
            for (int r = 0; r < 4; ++r) {
                float v = acc[r] + b1v[nt];
                v = v > 0.f ? v : 0.f;
                const int row = mrow + q * 4 + r;
                const int col = nt * 16 + i;
                sh[swz(row, col >> 3) + (col & 7)] = (_Float16)v;
            }
        }
        __syncthreads();  // h1 visible

        // ---- S2: h2 = relu(h1 @ W2 + b2) ----
        half8 aH[4];
        #pragma unroll
        for (int c = 0; c < 4; ++c)
            aH[c] = *(const half8*)(sh + swz(mrow + i, c * 4 + q));
        __syncthreads();  // all h1 reads done before h2 overwrite

        f32x4 acc2[8];
        #pragma unroll
        for (int nt = 0; nt < 8; ++nt) acc2[nt] = (f32x4){};
        #pragma unroll
        for (int nt = 0; nt < 8; ++nt) {
            #pragma unroll
            for (int c = 0; c < 4; ++c) {
                half8 bf = *(const half8*)(sW2T + swz(nt * 16 + i, c * 4 + q));
                acc2[nt] = __builtin_amdgcn_mfma_f32_16x16x32_f16(aH[c], bf, acc2[nt], 0, 0, 0);
            }
        }
        #pragma unroll
        for (int nt = 0; nt < 8; ++nt) {
            #pragma unroll
            for (int r = 0; r < 4; ++r) {
                float v = acc2[nt][r] + b2v[nt];
                v = v > 0.f ? v : 0.f;
                const int row = mrow + q * 4 + r;
                const int col = nt * 16 + i;
                sh[swz(row, col >> 3) + (col & 7)] = (_Float16)v;
            }
        }
        __syncthreads();  // h2 visible

        // ---- S3: resp = h2 @ W3 + b3 ----
        f32x4 acc3 = {};
        #pragma unroll
        for (int c = 0; c < 4; ++c) {
            half8 a2 = *(const half8*)(sh + swz(mrow + i, c * 4 + q));
            acc3 = __builtin_amdgcn_mfma_f32_16x16x32_f16(a2, bW3[c], acc3, 0, 0, 0);
        }

        // ---- claim bucket slot (lanes 0..15 = the wave's 16 electrons) ----
        unsigned int ridx = 0;
        if (lane < 16) {
            int bin = (int)x2;
            bin = bin < 0 ? 0 : (bin > TT - 1 ? TT - 1 : bin);
            unsigned int slot = atomicAdd(&cursor[bi * TT + bin], 1u);
            if (slot >= CAP) slot = CAP - 1;   // statistically unreachable
            ridx = (unsigned int)(bi * TT + bin) * CAP + slot;
        }

        // ---- write 32B records: per electron e=q*4+r, 8 lanes write 8 dwords ----
        #pragma unroll
        for (int r = 0; r < 4; ++r) {
            const int e = q * 4 + r;
            const unsigned int rx = __shfl(ridx, e);
            const float zr = __shfl(x2, e);
            const float cr = __shfl(coef, e);
            float val = acc3[r] + b3v;               // resp[s=i] (i<12)
            float val_hi = __shfl(val, lane + 1);
            float dv = 0.f;
            int f = -1;
            if (i < 12 && !(i & 1)) {
                __half2 h2;
                h2.x = __float2half(val);
                h2.y = __float2half(val_hi);
                dv = *(float*)&h2;
                f = 2 + (i >> 1);
            } else if (i == 12) { dv = zr; f = 0; }
            else if (i == 13)   { dv = cr; f = 1; }
            if (f >= 0)
                rec[(size_t)rx * REC_W + f] = dv;
        }
        __syncthreads();  // protect sh before next pass
    }
}

// ---------------- K2: block-cooperative gather ----------------
// Block = (b, 20-tick chunk). Stage 26 bins of records into LDS (coalesced,
// read once per block), then thread (t,s) sums its 7-bin window from LDS.
__global__ __launch_bounds__(256) void gather_kernel(
    const unsigned int* __restrict__ cursor,  // per-bin counts
    const float* __restrict__ rec,
    float* __restrict__ out)                  // (B, S, T)
{
    __shared__ float sz[NB * CAP];
    __shared__ float sc[NB * CAP];
    __shared__ unsigned int srsp[NB * CAP * 6];   // resp as 6 half2 words
    __shared__ unsigned int lcnt[NB];

    const int b = blockIdx.x / (TT / TB);
    const int t0 = (blockIdx.x % (TT / TB)) * TB;
    const int tid = threadIdx.x;
    const int wv = tid >> 6;
    const int ln = tid & 63;

    // ---- phase 1: stage bins [t0-3, t0+TB+2] ----
    for (int bb = wv; bb < NB; bb += 4) {
        const int g = t0 - 3 + bb;
        unsigned int c = 0;
        if (g >= 0 && g < TT) {
            c = cursor[b * TT + g];
            if (c > CAP) c = CAP;
        }
        if (ln == 0) lcnt[bb] = c;
        const float* src = rec + (size_t)(b * TT + g) * CAP * REC_W;
        for (unsigned int idx = ln; idx < c * 8u; idx += 64) {
            const unsigned int slot = idx >> 3;
            const unsigned int w = idx & 7;
            const float v = src[slot * REC_W + w];
            const int ls = bb * CAP + slot;
            if (w == 0)      sz[ls] = v;
            else if (w == 1) sc[ls] = v;
            else             srsp[ls * 6 + (w - 2)] = __float_as_uint(v);
        }
    }
    __syncthreads();

    // ---- phase 2: thread = (t_local, s) ----
    const int t_l = tid / SS;
    const int s = tid - t_l * SS;
    if (t_l >= TB) return;
    const int t = t0 + t_l;
    const float tf = (float)t;
    float acc = 0.f;
    #pragma unroll
    for (int o = 0; o < 7; ++o) {
        const int bb = t_l + o;           // bin g = t-3+o
        const unsigned int c = lcnt[bb];
        const int base = bb * CAP;
        for (unsigned int u = 0; u < c; ++u) {
            const int ls = base + u;
            const float z = sz[ls];
            const float cc = sc[ls];
            const float d = tf - z;
            const unsigned int rw = srsp[ls * 6 + (s >> 1)];
            const __half2 h2 = *(const __half2*)&rw;
            const float rv = (s & 1) ? __half2float(h2.y) : __half2float(h2.x);
            acc = fmaf(__expf(-5.0f * d * d) * cc, rv, acc);
        }
    }
    out[(b * SS + s) * TT + t] = acc;
}

extern "C" void kernel_launch(void* const* d_in, const int* in_sizes, int n_in,
                              void* d_out, int out_size, void* d_ws, size_t ws_size,
                              hipStream_t stream) {
    const float* de   = (const float*)d_in[0];
    const float* mask = (const float*)d_in[1];
    const float* W1   = (const float*)d_in[2];
    const float* b1   = (const float*)d_in[3];
    const float* W2   = (const float*)d_in[4];
    const float* b2   = (const float*)d_in[5];
    const float* W3   = (const float*)d_in[6];
    const float* b3   = (const float*)d_in[7];
    float* out = (float*)d_out;

    char* ws = (char*)d_ws;
    unsigned int* cursor = (unsigned int*)(ws + WS_CURSOR);
    float*        rec    = (float*)(ws + WS_REC);

    // cursor doubles as histogram; must start at zero every call.
    hipMemsetAsync(cursor, 0, BB * TT * sizeof(unsigned int), stream);

    mlp_kernel<<<625, 256, 0, stream>>>(de, mask, W1, b1, W2, b2, W3, b3,
                                        cursor, rec);
    gather_kernel<<<BB * (TT / TB), 256, 0, stream>>>(cursor, rec, out);
}

// Round 7
// 105.689 us; speedup vs baseline: 2.9974x; 1.0119x over previous
//
#include <hip/hip_runtime.h>
#include <hip/hip_fp16.h>

// Problem constants (from reference)
#define BB 8
#define NN 10000
#define TT 2000
#define SS 12
#define HH 128
#define TOTAL_E (BB * NN)           // 80000
#define COEF 1.2615662610100802f    // GAUSS_NORM / sqrt(BIN_SIGMA)

// Bucket sort: lambda ~ 5 electrons/bin; P(bin > 32) ~ 1e-16.
#define CAP 32
#define REC_W 8                     // dwords per record (32 B): z, coef, resp[12] f16

// Gather tiling
#define TB 20                       // ticks per block
#define NB 26                       // bins staged = TB + 6

// Workspace layout (bytes)
#define WS_CURSOR 0                 // 8*2000 u32 = 64 KB
#define WS_REC    65536             // 8*2000*32 rec * 32 B = 16.4 MB

typedef _Float16 half8 __attribute__((ext_vector_type(8)));
typedef float f32x4 __attribute__((ext_vector_type(4)));

// Swizzled LDS addressing for [row][128 halves] tiles: 16 chunks of 8 halves;
// phys_chunk = chunk ^ (row & 7) -> b128 frag reads are 2-way (free).
__device__ __forceinline__ int swz(int row, int chunk) {
    return row * 128 + ((chunk ^ (row & 7)) * 8);
}

// ---------------- K1: fully-MFMA MLP + bucketed 32B record write ----------------
__global__ __launch_bounds__(256) void mlp_kernel(
    const float* __restrict__ de,    // (B,N,3)
    const float* __restrict__ mask,  // (B,N)
    const float* __restrict__ W1, const float* __restrict__ b1,
    const float* __restrict__ W2, const float* __restrict__ b2,
    const float* __restrict__ W3, const float* __restrict__ b3,
    unsigned int* __restrict__ cursor,
    float* __restrict__ rec)
{
    __shared__ _Float16 sW2T[HH * 128];   // [n][k] transposed, swizzled, 32 KB
    __shared__ _Float16 sh[64 * 128];     // [m][k] h1 then h2, swizzled, 16 KB

    const int tid = threadIdx.x;
    const int wave = tid >> 6;
    const int lane = tid & 63;
    const int q = lane >> 4;      // quad 0..3
    const int i = lane & 15;      // tile row/col index

    // ---- stage W2^T -> LDS (f16, swizzled, b128 writes) ----
    {
        const int n = tid >> 1;
        const int kh = (tid & 1) * 8;
        #pragma unroll
        for (int c8 = 0; c8 < 8; ++c8) {
            const int c = kh + c8;
            half8 v;
            #pragma unroll
            for (int j = 0; j < 8; ++j)
                v[j] = (_Float16)W2[(c * 8 + j) * HH + n];   // W2[k][n]
            *(half8*)(sW2T + swz(n, c)) = v;
        }
    }

    // ---- loop-invariant fragments / biases ----
    half8 bW1[8];
    #pragma unroll
    for (int nt = 0; nt < 8; ++nt) {
        half8 f = {};
        if (q == 0) {
            const int n = nt * 16 + i;
            f[0] = (_Float16)W1[n];
            f[1] = (_Float16)W1[HH + n];
            f[2] = (_Float16)W1[2 * HH + n];
        }
        bW1[nt] = f;
    }
    half8 bW3[4];
    #pragma unroll
    for (int c = 0; c < 4; ++c) {
        half8 f = {};
        if (i < SS) {
            #pragma unroll
            for (int j = 0; j < 8; ++j)
                f[j] = (_Float16)W3[(c * 32 + q * 8 + j) * SS + i];
        }
        bW3[c] = f;
    }
    float b1v[8], b2v[8];
    #pragma unroll
    for (int nt = 0; nt < 8; ++nt) {
        b1v[nt] = b1[nt * 16 + i];
        b2v[nt] = b2[nt * 16 + i];
    }
    const float b3v = (i < SS) ? b3[i] : 0.f;

    __syncthreads();  // sW2T staged

    const int mrow = wave * 16;

    for (int base = blockIdx.x * 64; base < TOTAL_E; base += gridDim.x * 64) {
        const int m_glob = base + mrow + i;
        const int bi = m_glob / NN;
        const float x0 = de[m_glob * 3 + 0];
        const float x1 = de[m_glob * 3 + 1];
        const float x2 = de[m_glob * 3 + 2];   // = z
        const float coef = mask[m_glob] * COEF;

        half8 aX = {};
        if (q == 0) { aX[0] = (_Float16)x0; aX[1] = (_Float16)x1; aX[2] = (_Float16)x2; }

        // ---- S1: h1 = relu(x @ W1 + b1) ----
        #pragma unroll
        for (int nt = 0; nt < 8; ++nt) {
            f32x4 acc = {};
            acc = __builtin_amdgcn_mfma_f32_16x16x32_f16(aX, bW1[nt], acc, 0, 0, 0);
            #pragma unroll
            for (int r = 0; r < 4; ++r) {
                float v = acc[r] + b1v[nt];
                v = v > 0.f ? v : 0.f;
                const int row = mrow + q * 4 + r;
                const int col = nt * 16 + i;
                sh[swz(row, col >> 3) + (col & 7)] = (_Float16)v;
            }
        }
        __syncthreads();  // h1 visible

        // ---- S2: h2 = relu(h1 @ W2 + b2) ----
        half8 aH[4];
        #pragma unroll
        for (int c = 0; c < 4; ++c)
            aH[c] = *(const half8*)(sh + swz(mrow + i, c * 4 + q));
        __syncthreads();  // all h1 reads done before h2 overwrite

        f32x4 acc2[8];
        #pragma unroll
        for (int nt = 0; nt < 8; ++nt) acc2[nt] = (f32x4){};
        #pragma unroll
        for (int nt = 0; nt < 8; ++nt) {
            #pragma unroll
            for (int c = 0; c < 4; ++c) {
                half8 bf = *(const half8*)(sW2T + swz(nt * 16 + i, c * 4 + q));
                acc2[nt] = __builtin_amdgcn_mfma_f32_16x16x32_f16(aH[c], bf, acc2[nt], 0, 0, 0);
            }
        }
        #pragma unroll
        for (int nt = 0; nt < 8; ++nt) {
            #pragma unroll
            for (int r = 0; r < 4; ++r) {
                float v = acc2[nt][r] + b2v[nt];
                v = v > 0.f ? v : 0.f;
                const int row = mrow + q * 4 + r;
                const int col = nt * 16 + i;
                sh[swz(row, col >> 3) + (col & 7)] = (_Float16)v;
            }
        }
        __syncthreads();  // h2 visible

        // ---- S3: resp = h2 @ W3 + b3 ----
        f32x4 acc3 = {};
        #pragma unroll
        for (int c = 0; c < 4; ++c) {
            half8 a2 = *(const half8*)(sh + swz(mrow + i, c * 4 + q));
            acc3 = __builtin_amdgcn_mfma_f32_16x16x32_f16(a2, bW3[c], acc3, 0, 0, 0);
        }

        // ---- claim bucket slot (lanes 0..15 = the wave's 16 electrons) ----
        unsigned int ridx = 0;
        if (lane < 16) {
            int bin = (int)x2;
            bin = bin < 0 ? 0 : (bin > TT - 1 ? TT - 1 : bin);
            unsigned int slot = atomicAdd(&cursor[bi * TT + bin], 1u);
            if (slot >= CAP) slot = CAP - 1;   // statistically unreachable
            ridx = (unsigned int)(bi * TT + bin) * CAP + slot;
        }

        // ---- write 32B records: per electron e=q*4+r, 8 lanes write 8 dwords ----
        #pragma unroll
        for (int r = 0; r < 4; ++r) {
            const int e = q * 4 + r;
            const unsigned int rx = __shfl(ridx, e);
            const float zr = __shfl(x2, e);
            const float cr = __shfl(coef, e);
            float val = acc3[r] + b3v;               // resp[s=i] (i<12)
            float val_hi = __shfl(val, lane + 1);
            float dv = 0.f;
            int f = -1;
            if (i < 12 && !(i & 1)) {
                __half2 h2;
                h2.x = __float2half(val);
                h2.y = __float2half(val_hi);
                dv = *(float*)&h2;
                f = 2 + (i >> 1);
            } else if (i == 12) { dv = zr; f = 0; }
            else if (i == 13)   { dv = cr; f = 1; }
            if (f >= 0)
                rec[(size_t)rx * REC_W + f] = dv;
        }
        __syncthreads();  // protect sh before next pass
    }
}

// ---------------- K2: block-cooperative gather ----------------
// Block = (b, 20-tick chunk). Stage 26 bins of records into LDS (coalesced,
// read once per block), then thread (t,s) sums its 7-bin window from LDS.
__global__ __launch_bounds__(256) void gather_kernel(
    const unsigned int* __restrict__ cursor,  // per-bin counts
    const float* __restrict__ rec,
    float* __restrict__ out)                  // (B, S, T)
{
    __shared__ float sz[NB * CAP];
    __shared__ float sc[NB * CAP];
    __shared__ unsigned int srsp[NB * CAP * 6];   // resp as 6 half2 words
    __shared__ unsigned int lcnt[NB];

    const int b = blockIdx.x / (TT / TB);
    const int t0 = (blockIdx.x % (TT / TB)) * TB;
    const int tid = threadIdx.x;
    const int wv = tid >> 6;
    const int ln = tid & 63;

    // ---- phase 1: stage bins [t0-3, t0+TB+2] ----
    for (int bb = wv; bb < NB; bb += 4) {
        const int g = t0 - 3 + bb;
        unsigned int c = 0;
        if (g >= 0 && g < TT) {
            c = cursor[b * TT + g];
            if (c > CAP) c = CAP;
        }
        if (ln == 0) lcnt[bb] = c;
        const float* src = rec + (size_t)(b * TT + g) * CAP * REC_W;
        for (unsigned int idx = ln; idx < c * 8u; idx += 64) {
            const unsigned int slot = idx >> 3;
            const unsigned int w = idx & 7;
            const float v = src[slot * REC_W + w];
            const int ls = bb * CAP + slot;
            if (w == 0)      sz[ls] = v;
            else if (w == 1) sc[ls] = v;
            else             srsp[ls * 6 + (w - 2)] = __float_as_uint(v);
        }
    }
    __syncthreads();

    // ---- phase 2: thread = (t_local, s) ----
    const int t_l = tid / SS;
    const int s = tid - t_l * SS;
    if (t_l >= TB) return;
    const int t = t0 + t_l;
    const float tf = (float)t;
    float acc = 0.f;
    #pragma unroll
    for (int o = 0; o < 7; ++o) {
        const int bb = t_l + o;           // bin g = t-3+o
        const unsigned int c = lcnt[bb];
        const int base = bb * CAP;
        for (unsigned int u = 0; u < c; ++u) {
            const int ls = base + u;
            const float z = sz[ls];
            const float cc = sc[ls];
            const float d = tf - z;
            const unsigned int rw = srsp[ls * 6 + (s >> 1)];
            const __half2 h2 = *(const __half2*)&rw;
            const float rv = (s & 1) ? __half2float(h2.y) : __half2float(h2.x);
            acc = fmaf(__expf(-5.0f * d * d) * cc, rv, acc);
        }
    }
    out[(b * SS + s) * TT + t] = acc;
}

extern "C" void kernel_launch(void* const* d_in, const int* in_sizes, int n_in,
                              void* d_out, int out_size, void* d_ws, size_t ws_size,
                              hipStream_t stream) {
    const float* de   = (const float*)d_in[0];
    const float* mask = (const float*)d_in[1];
    const float* W1   = (const float*)d_in[2];
    const float* b1   = (const float*)d_in[3];
    const float* W2   = (const float*)d_in[4];
    const float* b2   = (const float*)d_in[5];
    const float* W3   = (const float*)d_in[6];
    const float* b3   = (const float*)d_in[7];
    float* out = (float*)d_out;

    char* ws = (char*)d_ws;
    unsigned int* cursor = (unsigned int*)(ws + WS_CURSOR);
    float*        rec    = (float*)(ws + WS_REC);

    // cursor doubles as histogram; must start at zero every call.
    hipMemsetAsync(cursor, 0, BB * TT * sizeof(unsigned int), stream);

    mlp_kernel<<<625, 256, 0, stream>>>(de, mask, W1, b1, W2, b2, W3, b3,
                                        cursor, rec);
    gather_kernel<<<BB * (TT / TB), 256, 0, stream>>>(cursor, rec, out);
}